// Round 3
// baseline (242.608 us; speedup 1.0000x reference)
//
#include <hip/hip_runtime.h>

// Problem constants
#define B_    16
#define N_    1024
#define DIN_  256
#define H_    4
#define F_    64
#define COUT_ 256
#define NEG_  0.2f

typedef __bf16 bf16x8 __attribute__((ext_vector_type(8)));
typedef float  f32x4  __attribute__((ext_vector_type(4)));
typedef unsigned short u16x8 __attribute__((ext_vector_type(8)));
typedef unsigned short u16x4 __attribute__((ext_vector_type(4)));

__device__ __forceinline__ unsigned short f2bf(float f) {
    unsigned u = __builtin_bit_cast(unsigned, f);
    u += 0x7fffu + ((u >> 16) & 1u);
    return (unsigned short)(u >> 16);
}

// ---------------------------------------------------------------------------
// Prep: blocks 0..255 transpose W -> Wt bf16 [H*F][DIN].
// Block 256: was/wad[h][d] = sum_f W[d,h,f] * a_{src,dst}[h,f].
// ---------------------------------------------------------------------------
__global__ __launch_bounds__(256) void prep_kernel(
    const float* __restrict__ W, const float* __restrict__ a_src,
    const float* __restrict__ a_dst, unsigned short* __restrict__ Wt,
    float* __restrict__ was, float* __restrict__ wad) {
    if (blockIdx.x < 256) {
        const int c = blockIdx.x, d = threadIdx.x;
        Wt[c * DIN_ + d] = f2bf(W[d * COUT_ + c]);
    } else {
        const int d = threadIdx.x;
#pragma unroll
        for (int h = 0; h < H_; h++) {
            float s = 0.f, t = 0.f;
#pragma unroll
            for (int f = 0; f < F_; f += 4) {
                f32x4 wv = *(const f32x4*)(W + d * COUT_ + h * F_ + f);
                f32x4 av = *(const f32x4*)(a_src + h * F_ + f);
                f32x4 bv = *(const f32x4*)(a_dst + h * F_ + f);
                s += wv[0]*av[0] + wv[1]*av[1] + wv[2]*av[2] + wv[3]*av[3];
                t += wv[0]*bv[0] + wv[1]*bv[1] + wv[2]*bv[2] + wv[3]*bv[3];
            }
            was[h * DIN_ + d] = s;
            wad[h * DIN_ + d] = t;
        }
    }
}

// ---------------------------------------------------------------------------
// E-logits: one wave per node row. e_src[b,h,i] = x[b,i,:] . was[h,:],
// e_dst likewise. Lane ln covers k = 4*ln..4*ln+3; 8 dots reduced together
// via shuffle. was/wad are 4KB -> L1/L2-hot after the first blocks.
// ---------------------------------------------------------------------------
__global__ __launch_bounds__(256) void e_kernel(
    const float* __restrict__ x, const float* __restrict__ was,
    const float* __restrict__ wad, float* __restrict__ e_src,
    float* __restrict__ e_dst) {
    const int row = blockIdx.x * 4 + (threadIdx.x >> 6);   // b*N + i
    const int b   = row >> 10;
    const int i   = row & (N_ - 1);
    const int ln  = threadIdx.x & 63;

    f32x4 xv = *(const f32x4*)(x + row * DIN_ + ln * 4);
    float s[H_], d[H_];
#pragma unroll
    for (int h = 0; h < H_; h++) {
        f32x4 wv = *(const f32x4*)(was + h * DIN_ + ln * 4);
        f32x4 uv = *(const f32x4*)(wad + h * DIN_ + ln * 4);
        s[h] = xv[0]*wv[0] + xv[1]*wv[1] + xv[2]*wv[2] + xv[3]*wv[3];
        d[h] = xv[0]*uv[0] + xv[1]*uv[1] + xv[2]*uv[2] + xv[3]*uv[3];
    }
#pragma unroll
    for (int off = 1; off <= 32; off <<= 1) {
#pragma unroll
        for (int h = 0; h < H_; h++) {
            s[h] += __shfl_xor(s[h], off);
            d[h] += __shfl_xor(d[h], off);
        }
    }
    if (ln == 0) {
#pragma unroll
        for (int h = 0; h < H_; h++) {
            e_src[(b * H_ + h) * N_ + i] = s[h];
            e_dst[(b * H_ + h) * N_ + i] = d[h];
        }
    }
}

// ---------------------------------------------------------------------------
// Kernel A: h = x @ W (bf16 MFMA), h_t stored [B][H][F][N].
// All 16 x-loads (f32x4) issued up front -> deep VMEM pipeline; converted to
// bf16 A-frags once; then pure MFMA + Wt-load (L2-hot) loop.
// 16-row i-tile: grid = B*(N/16) = 1024 blocks, wave = head.
// ---------------------------------------------------------------------------
__global__ __launch_bounds__(256, 4) void gat_h_kernel(
    const float* __restrict__ x, const unsigned short* __restrict__ Wt,
    unsigned short* __restrict__ h_t) {
    const int b   = blockIdx.x >> 6;
    const int it0 = (blockIdx.x & 63) * 16;
    const int w   = threadIdx.x >> 6;   // wave id == head
    const int ln  = threadIdx.x & 63;
    const int l15 = ln & 15;
    const int q   = ln >> 4;

    const float* xrow = x + (b * N_ + it0 + l15) * DIN_;

    // Preload entire K (256) for this lane's A-rows: 16 x f32x4 in flight.
    f32x4 xv[16];
#pragma unroll
    for (int it = 0; it < 8; it++) {
        xv[2 * it]     = *(const f32x4*)(xrow + it * 32 + q * 8);
        xv[2 * it + 1] = *(const f32x4*)(xrow + it * 32 + q * 8 + 4);
    }
    bf16x8 af[8];
#pragma unroll
    for (int it = 0; it < 8; it++) {
        u16x8 u;
#pragma unroll
        for (int jj = 0; jj < 4; jj++) {
            u[jj]     = f2bf(xv[2 * it][jj]);
            u[jj + 4] = f2bf(xv[2 * it + 1][jj]);
        }
        af[it] = __builtin_bit_cast(bf16x8, u);
    }

    f32x4 acc[4];
#pragma unroll
    for (int ft = 0; ft < 4; ft++) acc[ft] = (f32x4)0.0f;

#pragma unroll
    for (int it = 0; it < 8; it++) {
#pragma unroll
        for (int ft = 0; ft < 4; ft++) {
            const int c = w * F_ + ft * 16 + l15;
            bf16x8 bf = *((const bf16x8*)(Wt + c * DIN_ + it * 32 + q * 8));
            acc[ft] = __builtin_amdgcn_mfma_f32_16x16x32_bf16(af[it], bf, acc[ft], 0, 0, 0);
        }
    }

    // Store h_t bf16: D row = q*4+r (local i), col = ft*16+l15 (f).
#pragma unroll
    for (int ft = 0; ft < 4; ft++) {
        u16x4 hb;
#pragma unroll
        for (int r = 0; r < 4; r++) hb[r] = f2bf(acc[ft][r]);
        const int f    = ft * 16 + l15;
        const int addr = ((b * H_ + w) * F_ + f) * N_ + it0 + q * 4;
        *((u16x4*)(h_t + addr)) = hb;
    }
}

// ---------------------------------------------------------------------------
// Kernel C: fused mask/leaky/exp + (P @ h) MFMA + normalize + bias.
// 512-thread blocks: 8 waves = 4 heads x 2 j-halves. Each wave accumulates
// its half's P@H partial + row sums; LDS combine at the end. Grid = 1024
// blocks = 4 blocks/CU x 8 waves = 32 waves/CU (100% occupancy target).
// ---------------------------------------------------------------------------
__global__ __launch_bounds__(512, 8) void gat_attn_kernel(
    const float* __restrict__ adj, const unsigned short* __restrict__ h_t,
    const float* __restrict__ e_src, const float* __restrict__ e_dst,
    const float* __restrict__ bias, float* __restrict__ out) {
    const int b   = blockIdx.x >> 6;
    const int it0 = (blockIdx.x & 63) * 16;
    const int w8  = threadIdx.x >> 6;   // 0..7
    const int h   = w8 & 3;             // head
    const int jh  = w8 >> 2;            // j-half
    const int ln  = threadIdx.x & 63;
    const int l15 = ln & 15;
    const int q   = ln >> 4;

    __shared__ float lds_acc[H_][4][64][4];  // 16 KB
    __shared__ float lds_rs[H_][16];

    const float edv = e_dst[(b * H_ + h) * N_ + it0 + l15];
    const float* es_base          = e_src + (b * H_ + h) * N_;
    const unsigned short* hb_base = h_t + ((b * H_ + h) * F_ + l15) * N_;
    const float* adj_row          = adj + (b * N_ + it0 + l15) * N_;

    f32x4 acc[4];
#pragma unroll
    for (int ft = 0; ft < 4; ft++) acc[ft] = (f32x4)0.0f;
    float rs = 0.0f;

    const int j_beg = jh * (N_ / 2);
    for (int j0 = j_beg; j0 < j_beg + N_ / 2; j0 += 32) {
        const int jb = j0 + q * 8;
        // Issue all loads up front; rely on 32 waves/CU TLP for latency.
        bf16x8 bfr0 = *((const bf16x8*)(hb_base + 0 * 16 * N_ + jb));
        bf16x8 bfr1 = *((const bf16x8*)(hb_base + 1 * 16 * N_ + jb));
        bf16x8 bfr2 = *((const bf16x8*)(hb_base + 2 * 16 * N_ + jb));
        bf16x8 bfr3 = *((const bf16x8*)(hb_base + 3 * 16 * N_ + jb));
        f32x4 e0 = *(const f32x4*)(es_base + jb);
        f32x4 a0 = *(const f32x4*)(adj_row + jb);
        f32x4 e1 = *(const f32x4*)(es_base + jb + 4);
        f32x4 a1 = *(const f32x4*)(adj_row + jb + 4);

        u16x8 u;
        float rloc = 0.0f;
#pragma unroll
        for (int jj = 0; jj < 4; jj++) {
            float t  = edv + e0[jj];
            t        = fmaxf(t, NEG_ * t);              // leaky_relu
            float pe = __expf(t);
            float pv = (a0[jj] > 0.5f) ? pe : 0.0f;
            rloc += pv;
            u[jj] = __builtin_bit_cast(unsigned short, (__bf16)pv);
        }
#pragma unroll
        for (int jj = 0; jj < 4; jj++) {
            float t  = edv + e1[jj];
            t        = fmaxf(t, NEG_ * t);
            float pe = __expf(t);
            float pv = (a1[jj] > 0.5f) ? pe : 0.0f;
            rloc += pv;
            u[jj + 4] = __builtin_bit_cast(unsigned short, (__bf16)pv);
        }
        rs += rloc;
        bf16x8 afr = __builtin_bit_cast(bf16x8, u);
        acc[0] = __builtin_amdgcn_mfma_f32_16x16x32_bf16(afr, bfr0, acc[0], 0, 0, 0);
        acc[1] = __builtin_amdgcn_mfma_f32_16x16x32_bf16(afr, bfr1, acc[1], 0, 0, 0);
        acc[2] = __builtin_amdgcn_mfma_f32_16x16x32_bf16(afr, bfr2, acc[2], 0, 0, 0);
        acc[3] = __builtin_amdgcn_mfma_f32_16x16x32_bf16(afr, bfr3, acc[3], 0, 0, 0);
    }

    // Partial row sums: reduce over q; every lane holds sum for row l15.
    rs += __shfl_xor(rs, 16);
    rs += __shfl_xor(rs, 32);

    // Cross-j-half combine via LDS.
    if (jh == 1) {
#pragma unroll
        for (int ft = 0; ft < 4; ft++)
            *(f32x4*)&lds_acc[h][ft][ln][0] = acc[ft];
        if (ln < 16) lds_rs[h][ln] = rs;
    }
    __syncthreads();
    if (jh == 0) {
#pragma unroll
        for (int ft = 0; ft < 4; ft++) {
            f32x4 o = *(const f32x4*)&lds_acc[h][ft][ln][0];
            acc[ft] += o;
        }
        rs += lds_rs[h][l15];
        float rinv[4];
#pragma unroll
        for (int r = 0; r < 4; r++) rinv[r] = 1.0f / __shfl(rs, q * 4 + r);
#pragma unroll
        for (int ft = 0; ft < 4; ft++) {
            const float bv = bias[h * F_ + ft * 16 + l15];
#pragma unroll
            for (int r = 0; r < 4; r++) {
                const int i = it0 + q * 4 + r;
                const int c = h * F_ + ft * 16 + l15;
                out[(b * N_ + i) * COUT_ + c] = acc[ft][r] * rinv[r] + bv;
            }
        }
    }
}

// ---------------------------------------------------------------------------
// Workspace layout (bytes):
//   [0, 128K)        Wt   bf16 [256][256]
//   [128K, +4K)      was  f32 [H][DIN]
//   [+4K, +4K)       wad  f32 [H][DIN]
//   [136K, +8M)      h_t  bf16 [B][H][F][N]
//   [+8M, +256K)     e_src f32 [B][H][N]
//   [+256K, +256K)   e_dst f32 [B][H][N]
// ---------------------------------------------------------------------------
extern "C" void kernel_launch(void* const* d_in, const int* in_sizes, int n_in,
                              void* d_out, int out_size, void* d_ws, size_t ws_size,
                              hipStream_t stream) {
    const float* x     = (const float*)d_in[0];
    const float* adj   = (const float*)d_in[1];
    const float* W     = (const float*)d_in[2];
    const float* a_src = (const float*)d_in[3];
    const float* a_dst = (const float*)d_in[4];
    const float* bias  = (const float*)d_in[5];
    float* out = (float*)d_out;

    char* ws = (char*)d_ws;
    unsigned short* Wt  = (unsigned short*)ws;
    float* was          = (float*)(ws + 131072);
    float* wad          = (float*)(ws + 131072 + 4096);
    unsigned short* h_t = (unsigned short*)(ws + 131072 + 8192);
    float* e_src        = (float*)(ws + 131072 + 8192 + 8388608);
    float* e_dst        = (float*)(ws + 131072 + 8192 + 8388608 + 262144);

    prep_kernel<<<257, 256, 0, stream>>>(W, a_src, a_dst, Wt, was, wad);
    e_kernel<<<B_ * N_ / 4, 256, 0, stream>>>(x, was, wad, e_src, e_dst);
    gat_h_kernel<<<B_ * (N_ / 16), 256, 0, stream>>>(x, Wt, h_t);
    gat_attn_kernel<<<B_ * (N_ / 16), 512, 0, stream>>>(adj, h_t, e_src, e_dst, bias, out);
}

// Round 4
// 181.501 us; speedup vs baseline: 1.3367x; 1.3367x over previous
//
#include <hip/hip_runtime.h>

// Problem constants
#define B_    16
#define N_    1024
#define DIN_  256
#define H_    4
#define F_    64
#define COUT_ 256
#define NEG_  0.2f

typedef __bf16 bf16x8 __attribute__((ext_vector_type(8)));
typedef float  f32x4  __attribute__((ext_vector_type(4)));
typedef unsigned short u16x8 __attribute__((ext_vector_type(8)));
typedef unsigned short u16x4 __attribute__((ext_vector_type(4)));

__device__ __forceinline__ unsigned short f2bf(float f) {
    unsigned u = __builtin_bit_cast(unsigned, f);
    u += 0x7fffu + ((u >> 16) & 1u);
    return (unsigned short)(u >> 16);
}

// ---------------------------------------------------------------------------
// Prep: blocks 0..255: pack W into MFMA-B-frag order Wtp (1KB-contiguous
// frag loads for gat_h). Blocks 256..259: was/wad[h][d] (logit weights).
// ---------------------------------------------------------------------------
__global__ __launch_bounds__(256) void prep_kernel(
    const float* __restrict__ W, const float* __restrict__ a_src,
    const float* __restrict__ a_dst, unsigned short* __restrict__ Wtp,
    float* __restrict__ was, float* __restrict__ wad) {
    if (blockIdx.x < 256) {
        const int c = blockIdx.x, k = threadIdx.x;
        const int w = c >> 6, ft = (c >> 4) & 3, l15 = c & 15;
        const int it = k >> 5, q = (k >> 3) & 3, jj = k & 7;
        const int ln = q * 16 + l15;
        Wtp[((((w * 8 + it) * 4 + ft) * 64) + ln) * 8 + jj] = f2bf(W[k * COUT_ + c]);
    } else {
        const int h = blockIdx.x - 256;
        const int d = threadIdx.x;
        float s = 0.f, t = 0.f;
#pragma unroll
        for (int f = 0; f < F_; f += 4) {
            f32x4 wv = *(const f32x4*)(W + d * COUT_ + h * F_ + f);
            f32x4 av = *(const f32x4*)(a_src + h * F_ + f);
            f32x4 bv = *(const f32x4*)(a_dst + h * F_ + f);
            s += wv[0]*av[0] + wv[1]*av[1] + wv[2]*av[2] + wv[3]*av[3];
            t += wv[0]*bv[0] + wv[1]*bv[1] + wv[2]*bv[2] + wv[3]*bv[3];
        }
        was[h * DIN_ + d] = s;
        wad[h * DIN_ + d] = t;
    }
}

// ---------------------------------------------------------------------------
// Masker + e-logits. Mask part (blocks 0..511): adj -> transposed bitmask
// mask[(b*32+jc)*1024 + i]. E part (blocks 512..4607): wave per node row.
// ---------------------------------------------------------------------------
__global__ __launch_bounds__(256) void masker_kernel(
    const float* __restrict__ adj, const float* __restrict__ x,
    const float* __restrict__ was, const float* __restrict__ wad,
    unsigned int* __restrict__ mask, float* __restrict__ e_src,
    float* __restrict__ e_dst) {
    if (blockIdx.x < 512) {
        const int b  = blockIdx.x >> 5;
        const int jc = blockIdx.x & 31;
        const int t  = threadIdx.x;
#pragma unroll
        for (int s = 0; s < 4; s++) {
            const int r = t + s * 256;
            const float* arow = adj + (b * N_ + r) * N_ + jc * 32;
            unsigned u = 0;
#pragma unroll
            for (int k = 0; k < 8; k++) {
                f32x4 v = *(const f32x4*)(arow + k * 4);
#pragma unroll
                for (int i = 0; i < 4; i++)
                    u |= (v[i] > 0.5f) ? (1u << (k * 4 + i)) : 0u;
            }
            mask[(b * 32 + jc) * N_ + r] = u;
        }
    } else {
        const int row = (blockIdx.x - 512) * 4 + (threadIdx.x >> 6);  // b*N + i
        const int b   = row >> 10;
        const int i   = row & (N_ - 1);
        const int ln  = threadIdx.x & 63;
        f32x4 xv = *(const f32x4*)(x + row * DIN_ + ln * 4);
        float s[H_], d[H_];
#pragma unroll
        for (int h = 0; h < H_; h++) {
            f32x4 wv = *(const f32x4*)(was + h * DIN_ + ln * 4);
            f32x4 uv = *(const f32x4*)(wad + h * DIN_ + ln * 4);
            s[h] = xv[0]*wv[0] + xv[1]*wv[1] + xv[2]*wv[2] + xv[3]*wv[3];
            d[h] = xv[0]*uv[0] + xv[1]*uv[1] + xv[2]*uv[2] + xv[3]*uv[3];
        }
#pragma unroll
        for (int off = 1; off <= 32; off <<= 1)
#pragma unroll
            for (int h = 0; h < H_; h++) {
                s[h] += __shfl_xor(s[h], off);
                d[h] += __shfl_xor(d[h], off);
            }
        if (ln == 0)
#pragma unroll
            for (int h = 0; h < H_; h++) {
                e_src[(b * H_ + h) * N_ + i] = s[h];
                e_dst[(b * H_ + h) * N_ + i] = d[h];
            }
    }
}

// ---------------------------------------------------------------------------
// Kernel A: h = x @ W (bf16 MFMA) -> h_t [B][H][F][N].
// launch_bounds(256,2): the 16xf32x4 preload needs >128 VGPR (R3's (256,4)
// likely spilled to scratch). Wtp loads are 1KB contiguous. XCD swizzle.
// ---------------------------------------------------------------------------
__global__ __launch_bounds__(256, 2) void gat_h_kernel(
    const float* __restrict__ x, const unsigned short* __restrict__ Wtp,
    unsigned short* __restrict__ h_t) {
    const int b   = blockIdx.x & 15;
    const int it0 = (blockIdx.x >> 4) * 16;
    const int w   = threadIdx.x >> 6;   // wave id == head
    const int ln  = threadIdx.x & 63;
    const int l15 = ln & 15;
    const int q   = ln >> 4;

    const float* xrow = x + (b * N_ + it0 + l15) * DIN_;

    f32x4 xv[16];
#pragma unroll
    for (int it = 0; it < 8; it++) {
        xv[2 * it]     = *(const f32x4*)(xrow + it * 32 + q * 8);
        xv[2 * it + 1] = *(const f32x4*)(xrow + it * 32 + q * 8 + 4);
    }
    bf16x8 af[8];
#pragma unroll
    for (int it = 0; it < 8; it++) {
        u16x8 u;
#pragma unroll
        for (int jj = 0; jj < 4; jj++) {
            u[jj]     = f2bf(xv[2 * it][jj]);
            u[jj + 4] = f2bf(xv[2 * it + 1][jj]);
        }
        af[it] = __builtin_bit_cast(bf16x8, u);
    }

    f32x4 acc[4];
#pragma unroll
    for (int ft = 0; ft < 4; ft++) acc[ft] = (f32x4)0.0f;

    const unsigned short* wb = Wtp + (w * 8) * 4 * 64 * 8 + ln * 8;
#pragma unroll
    for (int it = 0; it < 8; it++) {
#pragma unroll
        for (int ft = 0; ft < 4; ft++) {
            bf16x8 bf = *((const bf16x8*)(wb + ((it * 4 + ft) * 64) * 8));
            acc[ft] = __builtin_amdgcn_mfma_f32_16x16x32_bf16(af[it], bf, acc[ft], 0, 0, 0);
        }
    }

#pragma unroll
    for (int ft = 0; ft < 4; ft++) {
        u16x4 hb;
#pragma unroll
        for (int r = 0; r < 4; r++) hb[r] = f2bf(acc[ft][r]);
        const int f    = ft * 16 + l15;
        const int addr = ((b * H_ + w) * F_ + f) * N_ + it0 + q * 4;
        *((u16x4*)(h_t + addr)) = hb;
    }
}

// ---------------------------------------------------------------------------
// Kernel C: fused mask/leaky/exp + (P @ h) MFMA + normalize + bias.
// 32-row waves (mt=2), wave = head, grid 512 (XCD-swizzled), all loads
// L2-hot. Row sums via 5th MFMA (all-ones B-frag): accs[mt][r] =
// rowsum(q*4+r) exactly where the epilogue needs it.
// ---------------------------------------------------------------------------
__global__ __launch_bounds__(256, 2) void gat_attn_kernel(
    const unsigned int* __restrict__ mask, const unsigned short* __restrict__ h_t,
    const float* __restrict__ e_src, const float* __restrict__ e_dst,
    const float* __restrict__ bias, float* __restrict__ out) {
    const int b   = blockIdx.x & 15;
    const int it0 = (blockIdx.x >> 4) * 32;
    const int h   = threadIdx.x >> 6;
    const int ln  = threadIdx.x & 63;
    const int l15 = ln & 15;
    const int q   = ln >> 4;

    float edv[2];
    edv[0] = e_dst[(b * H_ + h) * N_ + it0 + l15];
    edv[1] = e_dst[(b * H_ + h) * N_ + it0 + 16 + l15];

    const float* es_base          = e_src + (b * H_ + h) * N_;
    const unsigned short* hb_base = h_t + ((b * H_ + h) * F_ + l15) * N_;
    const unsigned int* mk_base   = mask + b * 32 * N_ + it0;

    f32x4 acc[2][4];
    f32x4 accs[2];
#pragma unroll
    for (int mt = 0; mt < 2; mt++) {
#pragma unroll
        for (int ft = 0; ft < 4; ft++) acc[mt][ft] = (f32x4)0.0f;
        accs[mt] = (f32x4)0.0f;
    }

    u16x8 ones_u;
#pragma unroll
    for (int jj = 0; jj < 8; jj++) ones_u[jj] = 0x3F80;   // bf16 1.0
    const bf16x8 ones = __builtin_bit_cast(bf16x8, ones_u);

    for (int j0 = 0; j0 < N_; j0 += 32) {
        const int jb = j0 + q * 8;
        bf16x8 bfr0 = *((const bf16x8*)(hb_base + 0 * 16 * N_ + jb));
        bf16x8 bfr1 = *((const bf16x8*)(hb_base + 1 * 16 * N_ + jb));
        bf16x8 bfr2 = *((const bf16x8*)(hb_base + 2 * 16 * N_ + jb));
        bf16x8 bfr3 = *((const bf16x8*)(hb_base + 3 * 16 * N_ + jb));
        f32x4 e0 = *(const f32x4*)(es_base + jb);
        f32x4 e1 = *(const f32x4*)(es_base + jb + 4);
        const unsigned int* mk = mk_base + (j0 >> 5) * N_;
        const unsigned m0 = mk[l15];
        const unsigned m1 = mk[16 + l15];

        float es8[8] = {e0[0], e0[1], e0[2], e0[3], e1[0], e1[1], e1[2], e1[3]};
        const unsigned mb0 = (m0 >> (q * 8)) & 0xffu;
        const unsigned mb1 = (m1 >> (q * 8)) & 0xffu;

        bf16x8 afr[2];
#pragma unroll
        for (int mt = 0; mt < 2; mt++) {
            const unsigned mb = mt ? mb1 : mb0;
            u16x8 u;
#pragma unroll
            for (int jj = 0; jj < 8; jj++) {
                float t  = edv[mt] + es8[jj];
                t        = fmaxf(t, NEG_ * t);             // leaky_relu
                float pe = __expf(t);
                float pv = ((mb >> jj) & 1u) ? pe : 0.0f;
                u[jj] = __builtin_bit_cast(unsigned short, (__bf16)pv);
            }
            afr[mt] = __builtin_bit_cast(bf16x8, u);
        }
#pragma unroll
        for (int mt = 0; mt < 2; mt++) {
            acc[mt][0] = __builtin_amdgcn_mfma_f32_16x16x32_bf16(afr[mt], bfr0, acc[mt][0], 0, 0, 0);
            acc[mt][1] = __builtin_amdgcn_mfma_f32_16x16x32_bf16(afr[mt], bfr1, acc[mt][1], 0, 0, 0);
            acc[mt][2] = __builtin_amdgcn_mfma_f32_16x16x32_bf16(afr[mt], bfr2, acc[mt][2], 0, 0, 0);
            acc[mt][3] = __builtin_amdgcn_mfma_f32_16x16x32_bf16(afr[mt], bfr3, acc[mt][3], 0, 0, 0);
            accs[mt]   = __builtin_amdgcn_mfma_f32_16x16x32_bf16(afr[mt], ones, accs[mt], 0, 0, 0);
        }
    }

    float bias_v[4];
#pragma unroll
    for (int ft = 0; ft < 4; ft++) bias_v[ft] = bias[h * F_ + ft * 16 + l15];

#pragma unroll
    for (int mt = 0; mt < 2; mt++) {
        f32x4 rinv;
#pragma unroll
        for (int r = 0; r < 4; r++) rinv[r] = 1.0f / accs[mt][r];
#pragma unroll
        for (int ft = 0; ft < 4; ft++)
#pragma unroll
            for (int r = 0; r < 4; r++) {
                const int i = it0 + mt * 16 + q * 4 + r;
                const int c = h * F_ + ft * 16 + l15;
                out[(b * N_ + i) * COUT_ + c] = acc[mt][ft][r] * rinv[r] + bias_v[ft];
            }
    }
}

// ---------------------------------------------------------------------------
// Workspace layout (bytes):
//   [0, 128K)      Wtp bf16 frag-packed | [128K,+4K) was | [+4K] wad
//   [136K, +8M)    h_t bf16 [B][H][F][N]
//   then e_src (256K), e_dst (256K), mask (2M). Total ~10.7 MB.
// ---------------------------------------------------------------------------
extern "C" void kernel_launch(void* const* d_in, const int* in_sizes, int n_in,
                              void* d_out, int out_size, void* d_ws, size_t ws_size,
                              hipStream_t stream) {
    const float* x     = (const float*)d_in[0];
    const float* adj   = (const float*)d_in[1];
    const float* W     = (const float*)d_in[2];
    const float* a_src = (const float*)d_in[3];
    const float* a_dst = (const float*)d_in[4];
    const float* bias  = (const float*)d_in[5];
    float* out = (float*)d_out;

    char* ws = (char*)d_ws;
    unsigned short* Wtp = (unsigned short*)ws;
    float* was          = (float*)(ws + 131072);
    float* wad          = (float*)(ws + 131072 + 4096);
    unsigned short* h_t = (unsigned short*)(ws + 139264);
    float* e_src        = (float*)(ws + 139264 + 8388608);
    float* e_dst        = (float*)(ws + 139264 + 8388608 + 262144);
    unsigned int* mask  = (unsigned int*)(ws + 139264 + 8388608 + 524288);

    prep_kernel<<<260, 256, 0, stream>>>(W, a_src, a_dst, Wtp, was, wad);
    masker_kernel<<<4608, 256, 0, stream>>>(adj, x, was, wad, mask, e_src, e_dst);
    gat_h_kernel<<<B_ * (N_ / 16), 256, 0, stream>>>(x, Wtp, h_t);
    gat_attn_kernel<<<B_ * (N_ / 32), 256, 0, stream>>>(mask, h_t, e_src, e_dst, bias, out);
}

// Round 5
// 155.940 us; speedup vs baseline: 1.5558x; 1.1639x over previous
//
#include <hip/hip_runtime.h>

// Problem constants
#define B_    16
#define N_    1024
#define DIN_  256
#define H_    4
#define F_    64
#define COUT_ 256
#define NEG_  0.2f
#define LOG2E_ 1.4426950408889634f

typedef __bf16 bf16x8 __attribute__((ext_vector_type(8)));
typedef float  f32x4  __attribute__((ext_vector_type(4)));
typedef unsigned short u16x8 __attribute__((ext_vector_type(8)));
typedef unsigned short u16x4 __attribute__((ext_vector_type(4)));
typedef unsigned int   u32x4 __attribute__((ext_vector_type(4)));

__device__ __forceinline__ unsigned short f2bf(float f) {
    unsigned u = __builtin_bit_cast(unsigned, f);
    u += 0x7fffu + ((u >> 16) & 1u);
    return (unsigned short)(u >> 16);
}

// ---------------------------------------------------------------------------
// Prep: pack W into MFMA-B-frag order Wtp (1KB-contiguous frag loads).
// Element (c,k): w=c>>6, ft=(c>>4)&3, l15=c&15, it=k>>5, q=(k>>3)&3, jj=k&7,
// ln=q*16+l15 -> Wtp[(((w*8+it)*4+ft)*64 + ln)*8 + jj].
// ---------------------------------------------------------------------------
__global__ __launch_bounds__(256) void prep_kernel(
    const float* __restrict__ W, unsigned short* __restrict__ Wtp) {
    const int c = blockIdx.x, k = threadIdx.x;
    const int w = c >> 6, ft = (c >> 4) & 3, l15 = c & 15;
    const int it = k >> 5, q = (k >> 3) & 3, jj = k & 7;
    const int ln = q * 16 + l15;
    Wtp[((((w * 8 + it) * 4 + ft) * 64) + ln) * 8 + jj] = f2bf(W[k * COUT_ + c]);
}

// ---------------------------------------------------------------------------
// Stage kernel: two independent parts split on blockIdx (block-uniform).
//
// Part 1 (blocks 0..2047, HBM-heavy, dispatched first): adj -> transposed
//   bitmask mask[(b*32+jc)*N + i]. One 32-bit word per thread (1 row-chunk).
//
// Part 2 (blocks 2048..3071): h = x @ W (bf16 MFMA). h stored FRAG-PACKED:
//   hp[b][h][jg(32)][ft(4)][ln(64)][8] so attn's B-frag loads are 1KB
//   lane-contiguous. e_src/e_dst computed in the epilogue from fp32 acc
//   (e = sum_f h*a), pre-scaled by log2(e) so attn uses v_exp_f32 directly.
// ---------------------------------------------------------------------------
__global__ __launch_bounds__(256, 4) void stage_kernel(
    const float* __restrict__ adj, const float* __restrict__ x,
    const unsigned short* __restrict__ Wtp, const float* __restrict__ a_src,
    const float* __restrict__ a_dst, unsigned int* __restrict__ mask,
    unsigned short* __restrict__ hp, float* __restrict__ e_src,
    float* __restrict__ e_dst) {
    if (blockIdx.x < 2048) {
        // ---- masker part ----
        const int b  = blockIdx.x >> 7;
        const int jc = (blockIdx.x >> 2) & 31;
        const int r  = (blockIdx.x & 3) * 256 + threadIdx.x;
        const float* arow = adj + (size_t)(b * N_ + r) * N_ + jc * 32;
        unsigned u = 0;
#pragma unroll
        for (int k = 0; k < 8; k++) {
            f32x4 v = *(const f32x4*)(arow + k * 4);
#pragma unroll
            for (int i2 = 0; i2 < 4; i2++)
                u |= (v[i2] > 0.5f) ? (1u << (k * 4 + i2)) : 0u;
        }
        mask[(b * 32 + jc) * N_ + r] = u;
    } else {
        // ---- gat_h part ----
        const int blk = blockIdx.x - 2048;
        const int b   = blk & 15;
        const int it0 = (blk >> 4) * 16;
        const int w   = threadIdx.x >> 6;   // wave id == head
        const int ln  = threadIdx.x & 63;
        const int l15 = ln & 15;
        const int q   = ln >> 4;

        const float* xrow = x + (size_t)(b * N_ + it0 + l15) * DIN_;

        // First half K (0..127) loads, then second half, then convert/MFMA
        // pipelined so the second half's VMEM overlaps the first MFMAs.
        f32x4 xv[8];
#pragma unroll
        for (int it = 0; it < 4; it++) {
            xv[2 * it]     = *(const f32x4*)(xrow + it * 32 + q * 8);
            xv[2 * it + 1] = *(const f32x4*)(xrow + it * 32 + q * 8 + 4);
        }
        f32x4 xw[8];
#pragma unroll
        for (int it = 0; it < 4; it++) {
            xw[2 * it]     = *(const f32x4*)(xrow + (it + 4) * 32 + q * 8);
            xw[2 * it + 1] = *(const f32x4*)(xrow + (it + 4) * 32 + q * 8 + 4);
        }
        bf16x8 af[4];
#pragma unroll
        for (int it = 0; it < 4; it++) {
            u16x8 u;
#pragma unroll
            for (int jj = 0; jj < 4; jj++) {
                u[jj]     = f2bf(xv[2 * it][jj]);
                u[jj + 4] = f2bf(xv[2 * it + 1][jj]);
            }
            af[it] = __builtin_bit_cast(bf16x8, u);
        }

        f32x4 acc[4];
#pragma unroll
        for (int ft = 0; ft < 4; ft++) acc[ft] = (f32x4)0.0f;

        const unsigned short* wb = Wtp + (w * 8) * 4 * 64 * 8 + ln * 8;
#pragma unroll
        for (int it = 0; it < 4; it++)
#pragma unroll
            for (int ft = 0; ft < 4; ft++) {
                bf16x8 bf = *((const bf16x8*)(wb + (it * 4 + ft) * 512));
                acc[ft] = __builtin_amdgcn_mfma_f32_16x16x32_bf16(af[it], bf, acc[ft], 0, 0, 0);
            }
        bf16x8 ag[4];
#pragma unroll
        for (int it = 0; it < 4; it++) {
            u16x8 u;
#pragma unroll
            for (int jj = 0; jj < 4; jj++) {
                u[jj]     = f2bf(xw[2 * it][jj]);
                u[jj + 4] = f2bf(xw[2 * it + 1][jj]);
            }
            ag[it] = __builtin_bit_cast(bf16x8, u);
        }
#pragma unroll
        for (int it = 0; it < 4; it++)
#pragma unroll
            for (int ft = 0; ft < 4; ft++) {
                bf16x8 bf = *((const bf16x8*)(wb + ((it + 4) * 4 + ft) * 512));
                acc[ft] = __builtin_amdgcn_mfma_f32_16x16x32_bf16(ag[it], bf, acc[ft], 0, 0, 0);
            }

        // Store h frag-packed. Lane holds h[i=it0+q*4+r][f=ft*16+l15];
        // hp element (jg, ft, ln'=q2*16+l15, jj') with jg=it0>>5,
        // q2=2*((it0>>4)&1)+(q>>1), jj'=(q&1)*4+r  -> contiguous u16x4.
        const int jg = it0 >> 5;
        const int q2 = 2 * ((it0 >> 4) & 1) + (q >> 1);
#pragma unroll
        for (int ft = 0; ft < 4; ft++) {
            u16x4 hb;
#pragma unroll
            for (int r = 0; r < 4; r++) hb[r] = f2bf(acc[ft][r]);
            const size_t addr =
                (size_t)((((b * H_ + w) * 32 + jg) * 4 + ft) * 64 + q2 * 16 + l15) * 8 + (q & 1) * 4;
            *((u16x4*)(hp + addr)) = hb;
        }

        // e logits from fp32 acc: e[i] = sum_f h[i,f]*a[f], scaled by log2e.
        float as_v[4], ad_v[4];
#pragma unroll
        for (int ft = 0; ft < 4; ft++) {
            as_v[ft] = a_src[w * F_ + ft * 16 + l15];
            ad_v[ft] = a_dst[w * F_ + ft * 16 + l15];
        }
        float ps[4], pd[4];
#pragma unroll
        for (int r = 0; r < 4; r++) {
            ps[r] = 0.0f; pd[r] = 0.0f;
#pragma unroll
            for (int ft = 0; ft < 4; ft++) {
                ps[r] += acc[ft][r] * as_v[ft];
                pd[r] += acc[ft][r] * ad_v[ft];
            }
        }
#pragma unroll
        for (int off = 1; off <= 8; off <<= 1)
#pragma unroll
            for (int r = 0; r < 4; r++) {
                ps[r] += __shfl_xor(ps[r], off);
                pd[r] += __shfl_xor(pd[r], off);
            }
        float vs = (l15 == 0) ? ps[0] : (l15 == 1) ? ps[1] : (l15 == 2) ? ps[2] : ps[3];
        float vd = (l15 == 0) ? pd[0] : (l15 == 1) ? pd[1] : (l15 == 2) ? pd[2] : pd[3];
        if (l15 < 4) {
            const int i = it0 + q * 4 + l15;
            e_src[(b * H_ + w) * N_ + i] = vs * LOG2E_;
            e_dst[(b * H_ + w) * N_ + i] = vd * LOG2E_;
        }
    }
}

// ---------------------------------------------------------------------------
// Kernel C: fused mask/leaky/exp2 + (P @ h) MFMA + normalize + bias.
// 512-thread blocks: 8 waves = 4 heads x 2 j-halves; LDS combine (40KB).
// Grid 512 -> 2 blocks/CU x 16 waves = 50% occupancy. Logits arrive
// pre-scaled by log2e so exp is a single v_exp_f32; bf16 pack is one
// v_perm_b32 per pair (truncation); rowsum via 5th MFMA (ones B-frag).
// ---------------------------------------------------------------------------
__global__ __launch_bounds__(512, 4) void gat_attn_kernel(
    const unsigned int* __restrict__ mask, const unsigned short* __restrict__ hp,
    const float* __restrict__ e_src, const float* __restrict__ e_dst,
    const float* __restrict__ bias, float* __restrict__ out) {
    const int b   = blockIdx.x & 15;
    const int it0 = (blockIdx.x >> 4) * 32;
    const int w8  = threadIdx.x >> 6;
    const int h   = w8 & 3;             // head
    const int jh  = w8 >> 2;            // j-half
    const int ln  = threadIdx.x & 63;
    const int l15 = ln & 15;
    const int q   = ln >> 4;

    __shared__ float lds[H_][2][5][64][4];   // 40 KB: acc[2][4] + accs[2]

    float edv[2];
    edv[0] = e_dst[(b * H_ + h) * N_ + it0 + l15];
    edv[1] = e_dst[(b * H_ + h) * N_ + it0 + 16 + l15];

    const float* es_base           = e_src + (b * H_ + h) * N_;
    const unsigned short* hp_base  = hp + (size_t)((b * H_ + h) * 32) * 2048 + ln * 8;
    const unsigned int* mk0        = mask + b * 32 * N_ + it0;

    f32x4 acc[2][4];
    f32x4 accs[2];
#pragma unroll
    for (int mt = 0; mt < 2; mt++) {
#pragma unroll
        for (int ft = 0; ft < 4; ft++) acc[mt][ft] = (f32x4)0.0f;
        accs[mt] = (f32x4)0.0f;
    }

    u16x8 ones_u;
#pragma unroll
    for (int jj = 0; jj < 8; jj++) ones_u[jj] = 0x3F80;   // bf16 1.0
    const bf16x8 ones = __builtin_bit_cast(bf16x8, ones_u);

    for (int jg = jh * 16; jg < jh * 16 + 16; jg++) {
        const int jb = jg * 32 + q * 8;
        const unsigned short* hf = hp_base + jg * 2048;
        bf16x8 bfr0 = *((const bf16x8*)(hf + 0 * 512));
        bf16x8 bfr1 = *((const bf16x8*)(hf + 1 * 512));
        bf16x8 bfr2 = *((const bf16x8*)(hf + 2 * 512));
        bf16x8 bfr3 = *((const bf16x8*)(hf + 3 * 512));
        f32x4 e0 = *(const f32x4*)(es_base + jb);
        f32x4 e1 = *(const f32x4*)(es_base + jb + 4);
        const unsigned m0 = mk0[jg * N_ + l15];
        const unsigned m1 = mk0[jg * N_ + 16 + l15];
        const unsigned mq0 = (m0 >> (q * 8)) & 0xffu;
        const unsigned mq1 = (m1 >> (q * 8)) & 0xffu;

        float es8[8] = {e0[0], e0[1], e0[2], e0[3], e1[0], e1[1], e1[2], e1[3]};

        bf16x8 afr[2];
#pragma unroll
        for (int mt = 0; mt < 2; mt++) {
            const unsigned mq = mt ? mq1 : mq0;
            u32x4 up;
#pragma unroll
            for (int p2 = 0; p2 < 4; p2++) {
                float t0 = edv[mt] + es8[2 * p2];
                float t1 = edv[mt] + es8[2 * p2 + 1];
                t0 = fmaxf(t0, NEG_ * t0);                 // leaky (log2-space)
                t1 = fmaxf(t1, NEG_ * t1);
                float p0 = __builtin_amdgcn_exp2f(t0);
                float p1 = __builtin_amdgcn_exp2f(t1);
                p0 = ((mq >> (2 * p2)) & 1u) ? p0 : 0.0f;
                p1 = ((mq >> (2 * p2 + 1)) & 1u) ? p1 : 0.0f;
                // pack two bf16 (truncate): one v_perm_b32
                up[p2] = __builtin_amdgcn_perm(__builtin_bit_cast(unsigned, p1),
                                               __builtin_bit_cast(unsigned, p0),
                                               0x07060302u);
            }
            afr[mt] = __builtin_bit_cast(bf16x8, up);
        }
#pragma unroll
        for (int mt = 0; mt < 2; mt++) {
            acc[mt][0] = __builtin_amdgcn_mfma_f32_16x16x32_bf16(afr[mt], bfr0, acc[mt][0], 0, 0, 0);
            acc[mt][1] = __builtin_amdgcn_mfma_f32_16x16x32_bf16(afr[mt], bfr1, acc[mt][1], 0, 0, 0);
            acc[mt][2] = __builtin_amdgcn_mfma_f32_16x16x32_bf16(afr[mt], bfr2, acc[mt][2], 0, 0, 0);
            acc[mt][3] = __builtin_amdgcn_mfma_f32_16x16x32_bf16(afr[mt], bfr3, acc[mt][3], 0, 0, 0);
            accs[mt]   = __builtin_amdgcn_mfma_f32_16x16x32_bf16(afr[mt], ones, accs[mt], 0, 0, 0);
        }
    }

    // Cross-j-half combine via LDS.
    if (jh == 1) {
#pragma unroll
        for (int mt = 0; mt < 2; mt++) {
#pragma unroll
            for (int ft = 0; ft < 4; ft++)
                *(f32x4*)&lds[h][mt][ft][ln][0] = acc[mt][ft];
            *(f32x4*)&lds[h][mt][4][ln][0] = accs[mt];
        }
    }
    __syncthreads();
    if (jh == 0) {
#pragma unroll
        for (int mt = 0; mt < 2; mt++) {
#pragma unroll
            for (int ft = 0; ft < 4; ft++)
                acc[mt][ft] += *(const f32x4*)&lds[h][mt][ft][ln][0];
            accs[mt] += *(const f32x4*)&lds[h][mt][4][ln][0];
        }
        float bias_v[4];
#pragma unroll
        for (int ft = 0; ft < 4; ft++) bias_v[ft] = bias[h * F_ + ft * 16 + l15];
#pragma unroll
        for (int mt = 0; mt < 2; mt++) {
            f32x4 rinv;
#pragma unroll
            for (int r = 0; r < 4; r++) rinv[r] = 1.0f / accs[mt][r];
#pragma unroll
            for (int ft = 0; ft < 4; ft++)
#pragma unroll
                for (int r = 0; r < 4; r++) {
                    const int i = it0 + mt * 16 + q * 4 + r;
                    const int c = h * F_ + ft * 16 + l15;
                    out[(size_t)(b * N_ + i) * COUT_ + c] = acc[mt][ft][r] * rinv[r] + bias_v[ft];
                }
        }
    }
}

// ---------------------------------------------------------------------------
// Workspace layout (bytes):
//   [0, 128K)    Wtp bf16 frag-packed [256][256]
//   [128K, +8M)  hp  bf16 frag-packed [B][H][32][4][64][8]
//   then e_src (256K), e_dst (256K), mask (2M). Total ~10.6 MB.
// ---------------------------------------------------------------------------
extern "C" void kernel_launch(void* const* d_in, const int* in_sizes, int n_in,
                              void* d_out, int out_size, void* d_ws, size_t ws_size,
                              hipStream_t stream) {
    const float* x     = (const float*)d_in[0];
    const float* adj   = (const float*)d_in[1];
    const float* W     = (const float*)d_in[2];
    const float* a_src = (const float*)d_in[3];
    const float* a_dst = (const float*)d_in[4];
    const float* bias  = (const float*)d_in[5];
    float* out = (float*)d_out;

    char* ws = (char*)d_ws;
    unsigned short* Wtp = (unsigned short*)ws;
    unsigned short* hp  = (unsigned short*)(ws + 131072);
    float* e_src        = (float*)(ws + 131072 + 8388608);
    float* e_dst        = (float*)(ws + 131072 + 8388608 + 262144);
    unsigned int* mask  = (unsigned int*)(ws + 131072 + 8388608 + 524288);

    prep_kernel<<<256, 256, 0, stream>>>(W, Wtp);
    stage_kernel<<<3072, 256, 0, stream>>>(adj, x, Wtp, a_src, a_dst, mask, hp, e_src, e_dst);
    gat_attn_kernel<<<512, 512, 0, stream>>>(mask, hp, e_src, e_dst, bias, out);
}

// Round 8
// 150.316 us; speedup vs baseline: 1.6140x; 1.0374x over previous
//
#include <hip/hip_runtime.h>

// Problem constants
#define B_    16
#define N_    1024
#define DIN_  256
#define H_    4
#define F_    64
#define COUT_ 256
#define NEG_  0.2f
#define LOG2E_ 1.4426950408889634f

typedef __bf16 bf16x8 __attribute__((ext_vector_type(8)));
typedef float  f32x4  __attribute__((ext_vector_type(4)));
typedef unsigned short u16x8 __attribute__((ext_vector_type(8)));
typedef unsigned short u16x4 __attribute__((ext_vector_type(4)));
typedef unsigned int   u32x4 __attribute__((ext_vector_type(4)));

__device__ __forceinline__ unsigned short f2bf(float f) {
    unsigned u = __builtin_bit_cast(unsigned, f);
    u += 0x7fffu + ((u >> 16) & 1u);
    return (unsigned short)(u >> 16);
}

// ---------------------------------------------------------------------------
// Prep: pack W into MFMA-B-frag order Wtp, bf16 (1KB-contiguous frag loads).
// Element (c,k): w=c>>6, ft=(c>>4)&3, l15=c&15, it=k>>5, q=(k>>3)&3, jj=k&7,
// ln=q*16+l15 -> Wtp[(((w*8+it)*4+ft)*64 + ln)*8 + jj].   [R5-proven]
// ---------------------------------------------------------------------------
__global__ __launch_bounds__(256) void prep_kernel(
    const float* __restrict__ W, unsigned short* __restrict__ Wtp) {
    const int c = blockIdx.x, k = threadIdx.x;
    const int w = c >> 6, ft = (c >> 4) & 3, l15 = c & 15;
    const int it = k >> 5, q = (k >> 3) & 3, jj = k & 7;
    const int ln = q * 16 + l15;
    Wtp[((((w * 8 + it) * 4 + ft) * 64) + ln) * 8 + jj] = f2bf(W[k * COUT_ + c]);
}

// ---------------------------------------------------------------------------
// Stage kernel.
// Part 1 (blocks 0..4095): adj -> transposed bitmask, COALESCED: one adj
//   row per wave (f32x4/lane x 4 chunks, contiguous 1KB/inst), nibble build
//   + 3x shfl_xor OR-reduce within 8-lane groups, (ln&7)==0 lanes store.
// Part 2 (blocks 4096..5119): h = x @ W via bf16 MFMA (R5 numerics) with x
//   staged through LDS (coalesced row loads, shared across all 4 waves).
//   hp frag-packed [b][h][jg][ft][ln][8] (R5 layout); e logits (x log2e)
//   from fp32 acc, stored f32 (R5 path).
// ---------------------------------------------------------------------------
__global__ __launch_bounds__(256, 4) void stage_kernel(
    const float* __restrict__ adj, const float* __restrict__ x,
    const unsigned short* __restrict__ Wtp, const float* __restrict__ a_src,
    const float* __restrict__ a_dst, unsigned int* __restrict__ mask,
    unsigned short* __restrict__ hp, float* __restrict__ e_src,
    float* __restrict__ e_dst) {
    __shared__ unsigned short xs[16][264];   // bf16 bits; padded row stride
    const int w  = threadIdx.x >> 6;
    const int ln = threadIdx.x & 63;

    if (blockIdx.x < 4096) {
        // ---- masker part: 1 row per wave, fully coalesced ----
        const int row = blockIdx.x * 4 + w;          // b*N + i, 0..16383
        const int b = row >> 10, i = row & (N_ - 1);
        const float* ar = adj + (size_t)row * N_ + ln * 4;
#pragma unroll
        for (int c = 0; c < 4; c++) {
            f32x4 v = *(const f32x4*)(ar + c * 256);
            unsigned nib = 0;
#pragma unroll
            for (int e = 0; e < 4; e++)
                nib |= (v[e] > 0.5f) ? (1u << e) : 0u;
            // lane ln covers cols c*256 + ln*4 .. +3 -> word bit (ln&7)*4+e
            unsigned word = nib << ((ln & 7) * 4);
            word |= __shfl_xor(word, 1);
            word |= __shfl_xor(word, 2);
            word |= __shfl_xor(word, 4);
            if ((ln & 7) == 0) {
                const int jc = c * 8 + (ln >> 3);
                mask[(b * 32 + jc) * N_ + i] = word;
            }
        }
    } else {
        // ---- gat_h part (bf16, R5 numerics, LDS-staged x) ----
        const int blk = blockIdx.x - 4096;
        const int b   = blk & 15;
        const int it0 = (blk >> 4) * 16;
        const int l15 = ln & 15;
        const int q   = ln >> 4;

        // Coalesced staging: wave w loads rows w*4..w*4+3 (1 row = 1KB inst),
        // converts to bf16 (RTNE), writes LDS once for all 4 waves.
#pragma unroll
        for (int s = 0; s < 4; s++) {
            const int row = w * 4 + s;
            f32x4 xv = *(const f32x4*)(x + (size_t)(b * N_ + it0 + row) * DIN_ + ln * 4);
            unsigned lo = (unsigned)f2bf(xv[0]) | ((unsigned)f2bf(xv[1]) << 16);
            unsigned hi = (unsigned)f2bf(xv[2]) | ((unsigned)f2bf(xv[3]) << 16);
            unsigned long long hb = (unsigned long long)lo | ((unsigned long long)hi << 32);
            *(unsigned long long*)&xs[row][ln * 4] = hb;
        }
        __syncthreads();

        f32x4 acc[4];
#pragma unroll
        for (int ft = 0; ft < 4; ft++) acc[ft] = (f32x4)0.0f;

        const unsigned short* wb = Wtp + (w * 8) * 4 * 64 * 8 + ln * 8;
#pragma unroll
        for (int it = 0; it < 8; it++) {
            bf16x8 af = *(const bf16x8*)&xs[l15][it * 32 + q * 8];
#pragma unroll
            for (int ft = 0; ft < 4; ft++) {
                bf16x8 bf = *((const bf16x8*)(wb + (it * 4 + ft) * 512));
                acc[ft] = __builtin_amdgcn_mfma_f32_16x16x32_bf16(af, bf, acc[ft], 0, 0, 0);
            }
        }

        // Store hp frag-packed (R5 layout). Lane holds h[i=it0+q*4+r][f=ft*16+l15].
        const int jg = it0 >> 5;
        const int q2 = 2 * ((it0 >> 4) & 1) + (q >> 1);
#pragma unroll
        for (int ft = 0; ft < 4; ft++) {
            u16x4 hb;
#pragma unroll
            for (int r = 0; r < 4; r++) hb[r] = f2bf(acc[ft][r]);
            const size_t addr =
                (size_t)((((b * H_ + w) * 32 + jg) * 4 + ft) * 64 + q2 * 16 + l15) * 8 + (q & 1) * 4;
            *((u16x4*)(hp + addr)) = hb;
        }

        // e logits from fp32 acc (x log2e), stored f32 (R5 path).
        float as_v[4], ad_v[4];
#pragma unroll
        for (int ft = 0; ft < 4; ft++) {
            as_v[ft] = a_src[w * F_ + ft * 16 + l15];
            ad_v[ft] = a_dst[w * F_ + ft * 16 + l15];
        }
        float ps[4], pd[4];
#pragma unroll
        for (int r = 0; r < 4; r++) {
            ps[r] = 0.0f; pd[r] = 0.0f;
#pragma unroll
            for (int ft = 0; ft < 4; ft++) {
                ps[r] += acc[ft][r] * as_v[ft];
                pd[r] += acc[ft][r] * ad_v[ft];
            }
        }
#pragma unroll
        for (int off = 1; off <= 8; off <<= 1)
#pragma unroll
            for (int r = 0; r < 4; r++) {
                ps[r] += __shfl_xor(ps[r], off);
                pd[r] += __shfl_xor(pd[r], off);
            }
        float vs = (l15 == 0) ? ps[0] : (l15 == 1) ? ps[1] : (l15 == 2) ? ps[2] : ps[3];
        float vd = (l15 == 0) ? pd[0] : (l15 == 1) ? pd[1] : (l15 == 2) ? pd[2] : pd[3];
        if (l15 < 4) {
            const int i = it0 + q * 4 + l15;
            e_src[(b * H_ + w) * N_ + i] = vs * LOG2E_;
            e_dst[(b * H_ + w) * N_ + i] = vd * LOG2E_;
        }
    }
}

// ---------------------------------------------------------------------------
// Kernel C: fused mask/leaky/exp2 + (P @ h) MFMA + normalize + bias.
// VERBATIM from R5 (passed, absmax 0.0039): 512-thread blocks, 8 waves =
// 4 heads x 2 j-halves, LDS combine; log2-prescaled f32 logits + exp2f;
// perm-truncation bf16 pack; rowsum via 5th MFMA (ones B-frag).
// ---------------------------------------------------------------------------
__global__ __launch_bounds__(512, 4) void gat_attn_kernel(
    const unsigned int* __restrict__ mask, const unsigned short* __restrict__ hp,
    const float* __restrict__ e_src, const float* __restrict__ e_dst,
    const float* __restrict__ bias, float* __restrict__ out) {
    const int b   = blockIdx.x & 15;
    const int it0 = (blockIdx.x >> 4) * 32;
    const int w8  = threadIdx.x >> 6;
    const int h   = w8 & 3;             // head
    const int jh  = w8 >> 2;            // j-half
    const int ln  = threadIdx.x & 63;
    const int l15 = ln & 15;
    const int q   = ln >> 4;

    __shared__ float lds[H_][2][5][64][4];   // 40 KB: acc[2][4] + accs[2]

    float edv[2];
    edv[0] = e_dst[(b * H_ + h) * N_ + it0 + l15];
    edv[1] = e_dst[(b * H_ + h) * N_ + it0 + 16 + l15];

    const float* es_base          = e_src + (b * H_ + h) * N_;
    const unsigned short* hp_base = hp + (size_t)((b * H_ + h) * 32) * 2048 + ln * 8;
    const unsigned int* mk0       = mask + b * 32 * N_ + it0;

    f32x4 acc[2][4];
    f32x4 accs[2];
#pragma unroll
    for (int mt = 0; mt < 2; mt++) {
#pragma unroll
        for (int ft = 0; ft < 4; ft++) acc[mt][ft] = (f32x4)0.0f;
        accs[mt] = (f32x4)0.0f;
    }

    u16x8 ones_u;
#pragma unroll
    for (int jj = 0; jj < 8; jj++) ones_u[jj] = 0x3F80;   // bf16 1.0
    const bf16x8 ones = __builtin_bit_cast(bf16x8, ones_u);

    for (int jg = jh * 16; jg < jh * 16 + 16; jg++) {
        const unsigned short* hf = hp_base + jg * 2048;
        bf16x8 bfr0 = *((const bf16x8*)(hf + 0 * 512));
        bf16x8 bfr1 = *((const bf16x8*)(hf + 1 * 512));
        bf16x8 bfr2 = *((const bf16x8*)(hf + 2 * 512));
        bf16x8 bfr3 = *((const bf16x8*)(hf + 3 * 512));
        f32x4 e0 = *(const f32x4*)(es_base + jg * 32 + q * 8);
        f32x4 e1 = *(const f32x4*)(es_base + jg * 32 + q * 8 + 4);
        const unsigned m0 = mk0[jg * N_ + l15];
        const unsigned m1 = mk0[jg * N_ + 16 + l15];

        float es8[8] = {e0[0], e0[1], e0[2], e0[3], e1[0], e1[1], e1[2], e1[3]};

        bf16x8 afr[2];
#pragma unroll
        for (int mt = 0; mt < 2; mt++) {
            const unsigned mq = ((mt ? m1 : m0) >> (q * 8)) & 0xffu;
            u32x4 up;
#pragma unroll
            for (int p2 = 0; p2 < 4; p2++) {
                float t0 = edv[mt] + es8[2 * p2];
                float t1 = edv[mt] + es8[2 * p2 + 1];
                t0 = fmaxf(t0, NEG_ * t0);                 // leaky (log2-space)
                t1 = fmaxf(t1, NEG_ * t1);
                float p0 = __builtin_amdgcn_exp2f(t0);
                float p1 = __builtin_amdgcn_exp2f(t1);
                p0 = ((mq >> (2 * p2)) & 1u) ? p0 : 0.0f;
                p1 = ((mq >> (2 * p2 + 1)) & 1u) ? p1 : 0.0f;
                up[p2] = __builtin_amdgcn_perm(__builtin_bit_cast(unsigned, p1),
                                               __builtin_bit_cast(unsigned, p0),
                                               0x07060302u);
            }
            afr[mt] = __builtin_bit_cast(bf16x8, up);
        }
#pragma unroll
        for (int mt = 0; mt < 2; mt++) {
            acc[mt][0] = __builtin_amdgcn_mfma_f32_16x16x32_bf16(afr[mt], bfr0, acc[mt][0], 0, 0, 0);
            acc[mt][1] = __builtin_amdgcn_mfma_f32_16x16x32_bf16(afr[mt], bfr1, acc[mt][1], 0, 0, 0);
            acc[mt][2] = __builtin_amdgcn_mfma_f32_16x16x32_bf16(afr[mt], bfr2, acc[mt][2], 0, 0, 0);
            acc[mt][3] = __builtin_amdgcn_mfma_f32_16x16x32_bf16(afr[mt], bfr3, acc[mt][3], 0, 0, 0);
            accs[mt]   = __builtin_amdgcn_mfma_f32_16x16x32_bf16(afr[mt], ones, accs[mt], 0, 0, 0);
        }
    }

    // Cross-j-half combine via LDS.
    if (jh == 1) {
#pragma unroll
        for (int mt = 0; mt < 2; mt++) {
#pragma unroll
            for (int ft = 0; ft < 4; ft++)
                *(f32x4*)&lds[h][mt][ft][ln][0] = acc[mt][ft];
            *(f32x4*)&lds[h][mt][4][ln][0] = accs[mt];
        }
    }
    __syncthreads();
    if (jh == 0) {
#pragma unroll
        for (int mt = 0; mt < 2; mt++) {
#pragma unroll
            for (int ft = 0; ft < 4; ft++)
                acc[mt][ft] += *(const f32x4*)&lds[h][mt][ft][ln][0];
            accs[mt] += *(const f32x4*)&lds[h][mt][4][ln][0];
        }
        float bias_v[4];
#pragma unroll
        for (int ft = 0; ft < 4; ft++) bias_v[ft] = bias[h * F_ + ft * 16 + l15];
#pragma unroll
        for (int mt = 0; mt < 2; mt++) {
            f32x4 rinv;
#pragma unroll
            for (int r = 0; r < 4; r++) rinv[r] = 1.0f / accs[mt][r];
#pragma unroll
            for (int ft = 0; ft < 4; ft++)
#pragma unroll
                for (int r = 0; r < 4; r++) {
                    const int i = it0 + mt * 16 + q * 4 + r;
                    const int c = h * F_ + ft * 16 + l15;
                    out[(size_t)(b * N_ + i) * COUT_ + c] = acc[mt][ft][r] * rinv[r] + bias_v[ft];
                }
        }
    }
}

// ---------------------------------------------------------------------------
// Workspace layout (bytes):
//   [0, 128K)    Wtp  bf16 frag-packed [256][256]
//   [128K, +8M)  hp   bf16 frag-packed [B][H][32][4][64][8]
//   +8M: e_src f32 (256K), e_dst f32 (256K), mask u32 (2M). Total ~10.7 MB.
// ---------------------------------------------------------------------------
extern "C" void kernel_launch(void* const* d_in, const int* in_sizes, int n_in,
                              void* d_out, int out_size, void* d_ws, size_t ws_size,
                              hipStream_t stream) {
    const float* x     = (const float*)d_in[0];
    const float* adj   = (const float*)d_in[1];
    const float* W     = (const float*)d_in[2];
    const float* a_src = (const float*)d_in[3];
    const float* a_dst = (const float*)d_in[4];
    const float* bias  = (const float*)d_in[5];
    float* out = (float*)d_out;

    char* ws = (char*)d_ws;
    unsigned short* Wtp = (unsigned short*)ws;
    unsigned short* hp  = (unsigned short*)(ws + 131072);
    float* e_src        = (float*)(ws + 131072 + 8388608);
    float* e_dst        = (float*)(ws + 131072 + 8388608 + 262144);
    unsigned int* mask  = (unsigned int*)(ws + 131072 + 8388608 + 524288);

    prep_kernel<<<256, 256, 0, stream>>>(W, Wtp);
    stage_kernel<<<5120, 256, 0, stream>>>(adj, x, Wtp, a_src, a_dst, mask, hp, e_src, e_dst);
    gat_attn_kernel<<<512, 512, 0, stream>>>(mask, hp, e_src, e_dst, bias, out);
}